// Round 10
// baseline (20239.461 us; speedup 1.0000x reference)
//
#include <hip/hip_runtime.h>
#include <math.h>

#define B_    32
#define S_    2048
#define DIN   256
#define H_    512
#define G_    2048
#define DOUT  256
#define T_    2048
#define NBLK  68

typedef __attribute__((ext_vector_type(8))) _Float16 f16x8;
typedef __attribute__((ext_vector_type(16))) float f32x16;

#define MFMA(a,b,c) __builtin_amdgcn_mfma_f32_32x32x16_f16((a),(b),(c),0,0,0)

// ---- ws byte offsets ----
#define OB_SLOT      0u          // 68 progress slots (int), 64B stride
#define OB_H0HH      16384u      // fp16 [4][32][512] ring = 131072 B each
#define OB_H0HL      147456u
#define OB_H1HH      278528u
#define OB_H1HL      409600u
#define OB_STATE_END 540672u
#define OB_B0        540672u     // fp32 [2048] combined bias (packed cols)
#define OB_B1        548864u
#define OB_WF        557056u     // fp16 [256][512]   Wfc^T
#define OB_W0        819200u     // fp16 [2048][768]  packed-col-major
#define OB_W1        3964928u    // fp16 [2048][1024]
#define OB_END       8159232u
#define OB_XHH       8159232u    // fp16 [32][2048][256] x split hi
#define OB_XHL       41713664u
#define OB_XEND      75268096u

// ---- dynamic LDS ----
#define LS_PT    131072          // W: [0,131072) ; Pt: float[3][32][64]
#define LS_TOTAL 155648

__device__ __forceinline__ float sigf(float v) {          // native exp2, NaN-safe
    return 1.0f / (1.0f + exp2f(-1.44269504f * v));
}
__device__ __forceinline__ float tanhfast(float v) {      // 1 - 2/(e+1), NaN-safe
    const float e = exp2f(2.88539008f * v);
    return 1.0f - 2.0f / (e + 1.0f);
}
__device__ __forceinline__ unsigned short h2u(_Float16 h) {
    union { _Float16 h; unsigned short u; } v; v.h = h; return v.u;
}

// 16B uncached (coherence-point) load; caller drains vmcnt before use.
__device__ __forceinline__ f16x8 ld128_coh(const unsigned short* p) {
    f16x8 r;
    asm volatile("global_load_dwordx4 %0, %1, off sc0 sc1"
                 : "=v"(r) : "v"(p) : "memory");
    return r;
}
__device__ __forceinline__ int ld_slot(const int* slots, int i) {
    return __hip_atomic_load(&slots[i * 16], __ATOMIC_RELAXED, __HIP_MEMORY_SCOPE_AGENT);
}

__device__ __forceinline__ int packcol(int p) {
    return (((p >> 2) & 3) * H_) + ((p >> 4) << 2) + (p & 3);
}

// ---- repack: W -> packed-col-major fp16 ----
__global__ __launch_bounds__(256) void repack_w(
    const float* __restrict__ s1, const float* __restrict__ s2,
    int k1, int K, int srcld, int dopack, unsigned short* __restrict__ dst)
{
    const int p  = blockIdx.x;
    const int kk = blockIdx.y * 256 + threadIdx.x;
    if (kk >= K) return;
    const int oc = dopack ? packcol(p) : p;
    const float w = (kk < k1) ? s1[(size_t)kk * srcld + oc]
                              : s2[(size_t)(kk - k1) * srcld + oc];
    dst[(size_t)p * K + kk] = h2u((_Float16)w);
}

__global__ __launch_bounds__(256) void repack_bias(
    const float* __restrict__ bx0, const float* __restrict__ bh0,
    const float* __restrict__ bx1, const float* __restrict__ bh1,
    char* __restrict__ wsb)
{
    const int q = blockIdx.x * 256 + threadIdx.x;
    if (q >= 2 * G_) return;
    const int p  = q & (G_ - 1);
    const int oc = packcol(p);
    float* dst = (float*)(wsb + (q < G_ ? OB_B0 : OB_B1));
    dst[p] = (q < G_) ? (bx0[oc] + bh0[oc]) : (bx1[oc] + bh1[oc]);
}

__global__ __launch_bounds__(256) void repack_x(const float* __restrict__ x, char* __restrict__ wsb)
{
    unsigned short* xhh = (unsigned short*)(wsb + OB_XHH);
    unsigned short* xhl = (unsigned short*)(wsb + OB_XHL);
    const size_t n = (size_t)B_ * S_ * DIN;
    for (size_t i = (size_t)blockIdx.x * 256 + threadIdx.x; i < n; i += (size_t)gridDim.x * 256) {
        const float v = x[i];
        const _Float16 hh = (_Float16)v;
        xhh[i] = h2u(hh);
        xhl[i] = h2u((_Float16)(v - (float)hh));
    }
}

// ---- per-role persistent loop ----
// ROLE 0: L0 (K=768, NSTEP=12)   blocks 0-31
// ROLE 1: L1 (K=1024, NSTEP=16)  blocks 32-63
// ROLE 2: FC (K=512,  NSTEP=8)   blocks 64-67
template<int ROLE, int NSTEP>
__device__ __forceinline__ void run_role(
    int bb, int tid, char* __restrict__ wsb,
    const float* __restrict__ x, const float* __restrict__ bfc,
    float* __restrict__ out, unsigned short* __restrict__ Wlds,
    float* __restrict__ Pt, int xsplit)
{
    const int lane = tid & 63, wave = tid >> 6;
    const int colc = lane & 31, halfl = lane >> 5;
    const int kq = wave & 3, cg = wave >> 2;
    const int K  = (ROLE == 0) ? 768 : (ROLE == 1 ? 1024 : 512);
    const int k0 = kq * (K >> 2);
    const int p0 = bb * 64;
    int* slots = (int*)(wsb + OB_SLOT);
    const int myslot = (ROLE == 0) ? bb : (ROLE == 1 ? 32 + bb : 64 + bb);

    // stage weight slice into LDS once: [(k8)*64 + col][8 fp16]
    {
        const unsigned short* Wg = (const unsigned short*)
            (wsb + (ROLE == 0 ? OB_W0 : ROLE == 1 ? OB_W1 : OB_WF));
        for (int idx = tid; idx < (K >> 3) * 64; idx += 512) {
            const int k8 = idx >> 6, cl = idx & 63;
            *(f16x8*)(Wlds + idx * 8) =
                *(const f16x8*)(Wg + ((size_t)(p0 + cl) * K + k8 * 8));
        }
    }
    __syncthreads();

    unsigned short* H0HH = (unsigned short*)(wsb + OB_H0HH);
    unsigned short* H0HL = (unsigned short*)(wsb + OB_H0HL);
    unsigned short* H1HH = (unsigned short*)(wsb + OB_H1HH);
    unsigned short* H1HL = (unsigned short*)(wsb + OB_H1HL);
    const unsigned short* XHH = (const unsigned short*)(wsb + OB_XHH);
    const unsigned short* XHL = (const unsigned short*)(wsb + OB_XHL);
    const float* Bp = (const float*)(wsb + (ROLE == 1 ? OB_B1 : OB_B0));

    // epilogue statics: thread (er, eu) owns unit j = bb*16 + eu, c in register
    const int er = tid >> 4, eu = tid & 15;
    float creg = 0.f;
    int sA = 0, sC = 0;   // register-cached progress

    for (int t = 0; t < T_; ++t) {
        f16x8 fh[NSTEP], fl[NSTEP];

        // ---- pass 1: x fragments (dep-free), issued before the wait ----
        if (ROLE == 0) {
            #pragma unroll
            for (int s = 0; s < NSTEP; ++s) {
                const int kf = k0 + s * 16;
                if (kf < 256) {
                    const size_t o = ((size_t)colc * S_ + t) * DIN + kf + halfl * 8;
                    if (xsplit) {
                        fh[s] = *(const f16x8*)(XHH + o);
                        fl[s] = *(const f16x8*)(XHL + o);
                    } else {
                        const float* xp = x + o;
                        #pragma unroll
                        for (int j = 0; j < 8; ++j) {
                            const float v = xp[j];
                            const _Float16 hh = (_Float16)v;
                            fh[s][j] = hh;
                            fl[s][j] = (_Float16)(v - (float)hh);
                        }
                    }
                }
            }
        }

        // ---- dataflow wait (wave 0; register-cached monotone slots) ----
        if (tid < 64) {
            if (ROLE == 0) {
                const int idx = lane;                         // 0-31 L0, 32-63 L1
                const int thr = (lane < 32) ? t : t - 3;
                for (;;) {
                    if (sA < thr) sA = ld_slot(slots, idx);
                    if (__all(sA >= thr)) break;
                    __builtin_amdgcn_s_sleep(1);
                }
            } else if (ROLE == 1) {
                const int idx = lane;                         // 0-31 L0, 32-63 L1
                const int thr = (lane < 32) ? t + 1 : t;
                const int tC  = t - 3;
                for (;;) {
                    bool ok = true;
                    if (sA < thr) sA = ld_slot(slots, idx);
                    ok = ok && (sA >= thr);
                    if (lane < 4) {
                        if (sC < tC) sC = ld_slot(slots, 64 + lane);
                        ok = ok && (sC >= tC);
                    }
                    if (__all(ok)) break;
                    __builtin_amdgcn_s_sleep(1);
                }
            } else {
                const int thr = t + 1;                        // L1 slots
                for (;;) {
                    if (lane < 32 && sA < thr) sA = ld_slot(slots, 32 + lane);
                    if (__all(lane >= 32 || sA >= thr)) break;
                    __builtin_amdgcn_s_sleep(1);
                }
            }
        }
        __syncthreads();

        // ---- pass 2: h fragments (uncached, batched) ----
        const int pw = t & 3, pr = (t + 3) & 3;
        #pragma unroll
        for (int s = 0; s < NSTEP; ++s) {
            const int kf = k0 + s * 16;
            const unsigned short *hh = 0, *hl = 0; int kk = 0; int slot = 0;
            bool ish = true;
            if (ROLE == 0) {
                if (kf < 256) ish = false;
                else { hh = H0HH; hl = H0HL; kk = kf - 256; slot = pr; }
            } else if (ROLE == 1) {
                if (kf < 512) { hh = H0HH; hl = H0HL; kk = kf;       slot = pw; }
                else          { hh = H1HH; hl = H1HL; kk = kf - 512; slot = pr; }
            } else            { hh = H1HH; hl = H1HL; kk = kf;       slot = pw; }
            if (ish) {
                const int off = slot * 16384 + colc * 512 + kk + halfl * 8;
                fh[s] = ld128_coh(hh + off);
                fl[s] = ld128_coh(hl + off);
            }
        }
        asm volatile("s_waitcnt vmcnt(0)" ::: "memory");
        __builtin_amdgcn_sched_barrier(0);

        // ---- MFMA: 2 per fragment pair (activations split, weights single) ----
        f32x16 acc;
        #pragma unroll
        for (int i = 0; i < 16; ++i) acc[i] = 0.f;
        #pragma unroll
        for (int s = 0; s < NSTEP; ++s) {
            const int k8a = ((k0 + s * 16) >> 3) + halfl;
            const f16x8 bw = *(const f16x8*)(Wlds + ((size_t)k8a * 64 + cg * 32 + colc) * 8);
            acc = MFMA(fh[s], bw, acc);
            acc = MFMA(fl[s], bw, acc);
        }

        // ---- cross-wave K-reduce: kq 1-3 store, kq 0 sums + bias ----
        if (kq != 0) {
            #pragma unroll
            for (int rg = 0; rg < 16; ++rg) {
                const int row = (rg & 3) + 8 * (rg >> 2) + 4 * halfl;
                Pt[((kq - 1) * 32 + row) * 64 + cg * 32 + colc] = acc[rg];
            }
        }
        __syncthreads();
        if (kq == 0) {
            #pragma unroll
            for (int rg = 0; rg < 16; ++rg) {
                const int row = (rg & 3) + 8 * (rg >> 2) + 4 * halfl;
                const int c = cg * 32 + colc;
                float v = acc[rg] + Pt[(0 * 32 + row) * 64 + c]
                                  + Pt[(1 * 32 + row) * 64 + c]
                                  + Pt[(2 * 32 + row) * 64 + c];
                v += (ROLE == 2) ? bfc[p0 + c] : Bp[p0 + c];
                Pt[row * 64 + c] = v;
            }
        }
        __syncthreads();

        // ---- epilogue ----
        if (ROLE == 2) {
            #pragma unroll
            for (int q = 0; q < 4; ++q) {
                const int c = eu * 4 + q;
                out[((size_t)er * S_ + t) * DOUT + p0 + c] = Pt[er * 64 + c];
            }
        } else {
            const int gq = eu >> 2, uu = eu & 3, cb = gq * 16 + uu;
            const float fg = Pt[er * 64 + cb + 0];
            const float ig = Pt[er * 64 + cb + 4];
            const float gg = Pt[er * 64 + cb + 8];
            const float og = Pt[er * 64 + cb + 12];
            const float cn = sigf(fg) * creg + sigf(ig) * tanhfast(gg);
            const float hn = sigf(og) * tanhfast(cn);
            creg = cn;
            const _Float16 hh16 = (_Float16)hn;
            const unsigned short uhh = h2u(hh16);
            const unsigned short uhl = h2u((_Float16)(hn - (float)hh16));
            const int ohh = __shfl_xor((int)uhh, 1);
            const int ohl = __shfl_xor((int)uhl, 1);
            if (!(eu & 1)) {
                const unsigned whh = (unsigned)uhh | ((unsigned)ohh << 16);
                const unsigned whl = (unsigned)uhl | ((unsigned)ohl << 16);
                const int off = pw * 16384 + er * 512 + bb * 16 + eu;   // even element
                unsigned short* DH = (ROLE == 0) ? H0HH : H1HH;
                unsigned short* DL = (ROLE == 0) ? H0HL : H1HL;
                __hip_atomic_store((unsigned*)(DH + off), whh,
                                   __ATOMIC_RELAXED, __HIP_MEMORY_SCOPE_AGENT);
                __hip_atomic_store((unsigned*)(DL + off), whl,
                                   __ATOMIC_RELAXED, __HIP_MEMORY_SCOPE_AGENT);
            }
        }

        // ---- publish (syncthreads drains each wave's stores first) ----
        __syncthreads();
        if (tid == 0)
            __hip_atomic_store(&((int*)(wsb + OB_SLOT))[myslot * 16], t + 1,
                               __ATOMIC_RELAXED, __HIP_MEMORY_SCOPE_AGENT);
    }
}

__global__ __launch_bounds__(512) void lstm_persist(
    const float* __restrict__ x, const float* __restrict__ bfc,
    float* __restrict__ out, char* __restrict__ wsb, int xsplit)
{
    extern __shared__ char smem[];
    unsigned short* Wlds = (unsigned short*)smem;
    float* Pt = (float*)(smem + LS_PT);
    const int blk = blockIdx.x, tid = threadIdx.x;
    if (blk < 32)       run_role<0, 12>(blk,      tid, wsb, x, bfc, out, Wlds, Pt, xsplit);
    else if (blk < 64)  run_role<1, 16>(blk - 32, tid, wsb, x, bfc, out, Wlds, Pt, xsplit);
    else                run_role<2, 8 >(blk - 64, tid, wsb, x, bfc, out, Wlds, Pt, xsplit);
}

extern "C" void kernel_launch(void* const* d_in, const int* in_sizes, int n_in,
                              void* d_out, int out_size, void* d_ws, size_t ws_size,
                              hipStream_t stream)
{
    const float* x   = (const float*)d_in[0];
    const float* Wx0 = (const float*)d_in[1];
    const float* bx0 = (const float*)d_in[2];
    const float* Wh0 = (const float*)d_in[3];
    const float* bh0 = (const float*)d_in[4];
    const float* Wx1 = (const float*)d_in[5];
    const float* bx1 = (const float*)d_in[6];
    const float* Wh1 = (const float*)d_in[7];
    const float* bh1 = (const float*)d_in[8];
    const float* Wfc = (const float*)d_in[9];
    const float* bfc = (const float*)d_in[10];
    float* out = (float*)d_out;
    char*  wsb = (char*)d_ws;

    const int xsplit = (ws_size >= OB_XEND) ? 1 : 0;

    // zero slots + h rings (inside the graph: every replay)
    hipMemsetAsync(d_ws, 0, OB_STATE_END, stream);

    repack_w<<<dim3(G_, 3), 256, 0, stream>>>(Wx0, Wh0, 256, 768, G_, 1,
        (unsigned short*)(wsb + OB_W0));
    repack_w<<<dim3(G_, 4), 256, 0, stream>>>(Wx1, Wh1, 512, 1024, G_, 1,
        (unsigned short*)(wsb + OB_W1));
    repack_w<<<dim3(DOUT, 2), 256, 0, stream>>>(Wfc, Wfc, 512, 512, DOUT, 0,
        (unsigned short*)(wsb + OB_WF));
    repack_bias<<<16, 256, 0, stream>>>(bx0, bh0, bx1, bh1, wsb);
    if (xsplit) repack_x<<<2048, 256, 0, stream>>>(x, wsb);

    hipFuncSetAttribute((const void*)lstm_persist,
                        hipFuncAttributeMaxDynamicSharedMemorySize, LS_TOTAL);
    lstm_persist<<<NBLK, 512, LS_TOTAL, stream>>>(x, bfc, out, wsb, xsplit);
}

// Round 12
// 9321.829 us; speedup vs baseline: 2.1712x; 2.1712x over previous
//
#include <hip/hip_runtime.h>
#include <math.h>

#define B_    32
#define S_    2048
#define DIN   256
#define H_    512
#define G_    2048
#define DOUT  256
#define T_    2048
#define NBLK  136

typedef __attribute__((ext_vector_type(8))) _Float16 f16x8;
typedef __attribute__((ext_vector_type(16))) float f32x16;

#define MFMA(a,b,c) __builtin_amdgcn_mfma_f32_32x32x16_f16((a),(b),(c),0,0,0)

// ---- ws byte offsets ----
#define OB_SLOT      0u          // 136 progress slots (int), 64B stride
#define OB_H0H       16384u      // fp16 [4][32][512] ring (32 KB/slot)
#define OB_H1H       147456u
#define OB_STATE_END 278528u
#define OB_B0        278528u     // fp32 [2048] combined bias (packed cols)
#define OB_B1        286720u
#define OB_WF        294912u     // fp16 [256][512]   Wfc^T
#define OB_W0        557056u     // fp16 [2048][768]  packed-col-major
#define OB_W1        3702784u    // fp16 [2048][1024]
#define OB_END       7897088u
#define OB_XH        7897088u    // fp16 [32][2048][256]
#define OB_XEND      41451520u

// ---- dynamic LDS ----
#define LS_PT    65536           // W: [0,65536) ; Pt: float[4][32][32]
#define LS_CST   81920           // float[256]
#define LS_TOTAL 82944

__device__ __forceinline__ float sigf(float v) {
    return 1.0f / (1.0f + exp2f(-1.44269504f * v));
}
__device__ __forceinline__ float tanhfast(float v) {
    const float e = exp2f(2.88539008f * v);
    return 1.0f - 2.0f / (e + 1.0f);
}
__device__ __forceinline__ unsigned short h2u(_Float16 h) {
    union { _Float16 h; unsigned short u; } v; v.h = h; return v.u;
}

// 16B uncached (coherence-point) load; caller drains vmcnt before use.
__device__ __forceinline__ f16x8 ld128_coh(const unsigned short* p) {
    f16x8 r;
    asm volatile("global_load_dwordx4 %0, %1, off sc0 sc1"
                 : "=v"(r) : "v"(p) : "memory");
    return r;
}
__device__ __forceinline__ int ld_slot(const int* slots, int i) {
    return __hip_atomic_load(&slots[i * 16], __ATOMIC_RELAXED, __HIP_MEMORY_SCOPE_AGENT);
}
__device__ __forceinline__ int packcol(int p) {
    return (((p >> 2) & 3) * H_) + ((p >> 4) << 2) + (p & 3);
}

// ---- repack: W -> packed-col-major fp16 ----
__global__ __launch_bounds__(256) void repack_w(
    const float* __restrict__ s1, const float* __restrict__ s2,
    int k1, int K, int srcld, int dopack, unsigned short* __restrict__ dst)
{
    const int p  = blockIdx.x;
    const int kk = blockIdx.y * 256 + threadIdx.x;
    if (kk >= K) return;
    const int oc = dopack ? packcol(p) : p;
    const float w = (kk < k1) ? s1[(size_t)kk * srcld + oc]
                              : s2[(size_t)(kk - k1) * srcld + oc];
    dst[(size_t)p * K + kk] = h2u((_Float16)w);
}

__global__ __launch_bounds__(256) void repack_bias(
    const float* __restrict__ bx0, const float* __restrict__ bh0,
    const float* __restrict__ bx1, const float* __restrict__ bh1,
    char* __restrict__ wsb)
{
    const int q = blockIdx.x * 256 + threadIdx.x;
    if (q >= 2 * G_) return;
    const int p  = q & (G_ - 1);
    const int oc = packcol(p);
    float* dst = (float*)(wsb + (q < G_ ? OB_B0 : OB_B1));
    dst[p] = (q < G_) ? (bx0[oc] + bh0[oc]) : (bx1[oc] + bh1[oc]);
}

__global__ __launch_bounds__(256) void repack_x(const float* __restrict__ x, char* __restrict__ wsb)
{
    unsigned short* xh = (unsigned short*)(wsb + OB_XH);
    const size_t n = (size_t)B_ * S_ * DIN;
    for (size_t i = (size_t)blockIdx.x * 256 + threadIdx.x; i < n; i += (size_t)gridDim.x * 256)
        xh[i] = h2u((_Float16)x[i]);
}

// ---- per-phase matmul body: batch A loads (16B uncached), drain, MFMA ----
template<int ROLE, int NSTEP>
__device__ __forceinline__ void phase_mm(
    int k0, int colc, int halfl, int t, int xsplit,
    const float* __restrict__ x, const unsigned short* __restrict__ XH,
    const unsigned short* A0, const unsigned short* A1,
    const unsigned short* Wlds, f32x16& acc)
{
    f16x8 fh[NSTEP];
    #pragma unroll
    for (int s = 0; s < NSTEP; ++s) {
        const int kf = k0 + s * 16;
        if (ROLE == 0 && kf < 256) {
            const size_t o = ((size_t)colc * S_ + t) * DIN + kf + halfl * 8;
            if (xsplit) {
                fh[s] = *(const f16x8*)(XH + o);
            } else {
                const float* xp = x + o;
                #pragma unroll
                for (int j = 0; j < 8; ++j) fh[s][j] = (_Float16)xp[j];
            }
        } else {
            const unsigned short* src; int kk;
            if (ROLE == 0)      { src = A1; kk = kf - 256; }
            else if (ROLE == 1) {
                if (kf < 512)   { src = A0; kk = kf; }
                else            { src = A1; kk = kf - 512; }
            } else              { src = A0; kk = kf; }
            fh[s] = ld128_coh(src + colc * 512 + kk + halfl * 8);
        }
    }
    asm volatile("s_waitcnt vmcnt(0)" ::: "memory");
    __builtin_amdgcn_sched_barrier(0);

    #pragma unroll
    for (int s = 0; s < NSTEP; ++s) {
        const int k8a = ((k0 + s * 16) >> 3) + halfl;
        const f16x8 bw = *(const f16x8*)(Wlds + (k8a * 32 + colc) * 8);
        acc = MFMA(fh[s], bw, acc);
    }
}

// ---- persistent dataflow kernel ----
// blocks [0,64): layer0; [64,128): layer1; [128,136): FC.  All loop t=0..2047.
// slots[i] = timesteps completed by block i (monotone).
__global__ __launch_bounds__(512, 2) void lstm_persist(
    const float* __restrict__ x, const float* __restrict__ bfc,
    float* __restrict__ out, char* __restrict__ wsb, int xsplit)
{
    extern __shared__ char smem[];
    unsigned short* Wlds = (unsigned short*)smem;
    float* Pt   = (float*)(smem + LS_PT);
    float* cstL = (float*)(smem + LS_CST);
    int* slots  = (int*)(wsb + OB_SLOT);

    const int blk = blockIdx.x, tid = threadIdx.x;
    const int wave = tid >> 6, lane = tid & 63;
    const int colc = lane & 31, halfl = lane >> 5;

    int role, bb;
    if (blk < 64)       { role = 0; bb = blk; }
    else if (blk < 128) { role = 1; bb = blk - 64; }
    else                { role = 2; bb = blk - 128; }

    const int K  = (role == 0) ? 768 : (role == 1 ? 1024 : 512);
    const int p0 = bb * 32;

    // stage weight slice into LDS once: [k8*32 + col][8 fp16]
    {
        const unsigned short* Wg = (const unsigned short*)
            (wsb + (role == 0 ? OB_W0 : role == 1 ? OB_W1 : OB_WF));
        const int nk8 = K >> 3;
        for (int idx = tid; idx < nk8 * 32; idx += 512) {
            const int k8 = idx >> 5, cl = idx & 31;
            *(f16x8*)(Wlds + idx * 8) =
                *(const f16x8*)(Wg + ((size_t)(p0 + cl) * K + k8 * 8));
        }
    }
    for (int i = tid; i < 256; i += 512) cstL[i] = 0.f;
    __syncthreads();

    unsigned short* H0H = (unsigned short*)(wsb + OB_H0H);
    unsigned short* H1H = (unsigned short*)(wsb + OB_H1H);
    const unsigned short* XH = (const unsigned short*)(wsb + OB_XH);
    const float* Bp = (const float*)(wsb + (role == 1 ? OB_B1 : OB_B0));

    const int k0 = wave * (K >> 3);
    int sA = 0, sB = 0, sC = 0;   // register-cached monotone progress (R9 structure)

    for (int t = 0; t < T_; ++t) {
        // ---- dataflow wait (wave 0 polls; full producer sets, R9-proven) ----
        if (tid < 64) {
            if (role == 0) {
                const int tA = t, tB = t - 3;              // own L0 >= t, L1 >= t-3
                for (;;) {
                    bool ok = true;
                    if (sA < tA) sA = ld_slot(slots, lane);        // L0 slots 0..63
                    ok = ok && (sA >= tA);
                    if (sB < tB) sB = ld_slot(slots, 64 + lane);   // L1 slots 64..127
                    ok = ok && (sB >= tB);
                    if (__all(ok)) break;
                    __builtin_amdgcn_s_sleep(1);
                }
            } else if (role == 1) {
                const int tA = t + 1, tB = t, tC = t - 3;  // L0 >= t+1, own >= t, FC >= t-3
                for (;;) {
                    bool ok = true;
                    if (sA < tA) sA = ld_slot(slots, lane);        // L0 slots 0..63
                    ok = ok && (sA >= tA);
                    if (sB < tB) sB = ld_slot(slots, 64 + lane);   // L1 slots 64..127
                    ok = ok && (sB >= tB);
                    if (lane < 8) {
                        if (sC < tC) sC = ld_slot(slots, 128 + lane);  // FC slots
                        ok = ok && (sC >= tC);
                    }
                    if (__all(ok)) break;
                    __builtin_amdgcn_s_sleep(1);
                }
            } else {
                const int tA = t + 1;                      // L1 >= t+1
                for (;;) {
                    if (sA < tA) sA = ld_slot(slots, 64 + lane);   // L1 slots 64..127
                    if (__all(sA >= tA)) break;
                    __builtin_amdgcn_s_sleep(1);
                }
            }
        }
        __syncthreads();

        const int pw = t & 3, pr = (t + 3) & 3;
        const unsigned short *A0 = 0, *A1 = 0;
        if (role == 0)      { A1 = H0H + pr * 16384; }
        else if (role == 1) { A0 = H0H + pw * 16384; A1 = H1H + pr * 16384; }
        else                { A0 = H1H + pw * 16384; }

        f32x16 acc;
        #pragma unroll
        for (int i = 0; i < 16; ++i) acc[i] = 0.f;

        if (role == 0)
            phase_mm<0, 6>(k0, colc, halfl, t, xsplit, x, XH, A0, A1, Wlds, acc);
        else if (role == 1)
            phase_mm<1, 8>(k0, colc, halfl, t, xsplit, x, XH, A0, A1, Wlds, acc);
        else
            phase_mm<2, 4>(k0, colc, halfl, t, xsplit, x, XH, A0, A1, Wlds, acc);

        // cross-wave K-reduce: waves 4-7 store, waves 0-3 accumulate
        if (wave >= 4) {
            #pragma unroll
            for (int rg = 0; rg < 16; ++rg) {
                const int row = (rg & 3) + 8 * (rg >> 2) + 4 * halfl;
                Pt[(wave - 4) * 1024 + row * 32 + colc] = acc[rg];
            }
        }
        __syncthreads();
        if (wave < 4) {
            #pragma unroll
            for (int rg = 0; rg < 16; ++rg) {
                const int row = (rg & 3) + 8 * (rg >> 2) + 4 * halfl;
                Pt[wave * 1024 + row * 32 + colc] += acc[rg];
            }
        }
        __syncthreads();

        if (role == 2) {
            #pragma unroll
            for (int ii = 0; ii < 2; ++ii) {
                const int idx = tid * 2 + ii;
                const int r = idx >> 5, c = idx & 31;
                const float v = Pt[idx] + Pt[1024 + idx] + Pt[2048 + idx] + Pt[3072 + idx]
                              + bfc[p0 + c];
                out[((size_t)r * S_ + t) * DOUT + p0 + c] = v;
            }
        } else {
            #pragma unroll
            for (int ii = 0; ii < 2; ++ii) {
                const int idx = tid * 2 + ii;
                Pt[idx] = Pt[idx] + Pt[1024 + idx] + Pt[2048 + idx] + Pt[3072 + idx]
                        + Bp[p0 + (idx & 31)];
            }
            __syncthreads();
            if (tid < 128) {
                const int r = tid >> 2, u2 = (tid & 3) * 2;      // units u2, u2+1
                const int cb = ((u2 >> 2) << 4) + (u2 & 3);
                unsigned short uh[2];
                #pragma unroll
                for (int uu = 0; uu < 2; ++uu) {
                    const float fg = Pt[r * 32 + cb + uu + 0];
                    const float ig = Pt[r * 32 + cb + uu + 4];
                    const float gg = Pt[r * 32 + cb + uu + 8];
                    const float og = Pt[r * 32 + cb + uu + 12];
                    const float cv = cstL[r * 8 + u2 + uu];
                    const float cn = sigf(fg) * cv + sigf(ig) * tanhfast(gg);
                    const float hn = sigf(og) * tanhfast(cn);
                    cstL[r * 8 + u2 + uu] = cn;
                    uh[uu] = h2u((_Float16)hn);
                }
                const unsigned wv = (unsigned)uh[0] | ((unsigned)uh[1] << 16);
                const int off = pw * 16384 + r * 512 + bb * 8 + u2;   // even element
                unsigned short* DH = (role == 0) ? H0H : H1H;
                __hip_atomic_store((unsigned*)(DH + off), wv,
                                   __ATOMIC_RELAXED, __HIP_MEMORY_SCOPE_AGENT);
            }
        }

        // ---- publish (syncthreads drains each wave's stores first) ----
        __syncthreads();
        if (tid == 0)
            __hip_atomic_store(&slots[blk * 16], t + 1,
                               __ATOMIC_RELAXED, __HIP_MEMORY_SCOPE_AGENT);
    }
}

extern "C" void kernel_launch(void* const* d_in, const int* in_sizes, int n_in,
                              void* d_out, int out_size, void* d_ws, size_t ws_size,
                              hipStream_t stream)
{
    const float* x   = (const float*)d_in[0];
    const float* Wx0 = (const float*)d_in[1];
    const float* bx0 = (const float*)d_in[2];
    const float* Wh0 = (const float*)d_in[3];
    const float* bh0 = (const float*)d_in[4];
    const float* Wx1 = (const float*)d_in[5];
    const float* bx1 = (const float*)d_in[6];
    const float* Wh1 = (const float*)d_in[7];
    const float* bh1 = (const float*)d_in[8];
    const float* Wfc = (const float*)d_in[9];
    const float* bfc = (const float*)d_in[10];
    float* out = (float*)d_out;
    char*  wsb = (char*)d_ws;

    const int xsplit = (ws_size >= OB_XEND) ? 1 : 0;

    hipMemsetAsync(d_ws, 0, OB_STATE_END, stream);

    repack_w<<<dim3(G_, 3), 256, 0, stream>>>(Wx0, Wh0, 256, 768, G_, 1,
        (unsigned short*)(wsb + OB_W0));
    repack_w<<<dim3(G_, 4), 256, 0, stream>>>(Wx1, Wh1, 512, 1024, G_, 1,
        (unsigned short*)(wsb + OB_W1));
    repack_w<<<dim3(DOUT, 2), 256, 0, stream>>>(Wfc, Wfc, 512, 512, DOUT, 0,
        (unsigned short*)(wsb + OB_WF));
    repack_bias<<<16, 256, 0, stream>>>(bx0, bh0, bx1, bh1, wsb);
    if (xsplit) repack_x<<<2048, 256, 0, stream>>>(x, wsb);

    hipFuncSetAttribute((const void*)lstm_persist,
                        hipFuncAttributeMaxDynamicSharedMemorySize, LS_TOTAL);
    lstm_persist<<<NBLK, 512, LS_TOTAL, stream>>>(x, bfc, out, wsb, xsplit);
}

// Round 14
// 9205.635 us; speedup vs baseline: 2.1986x; 1.0126x over previous
//
#include <hip/hip_runtime.h>
#include <math.h>

#define B_    32
#define S_    2048
#define DIN   256
#define H_    512
#define G_    2048
#define DOUT  256
#define T_    2048
#define NBLK  200

typedef __attribute__((ext_vector_type(8))) _Float16 f16x8;
typedef __attribute__((ext_vector_type(16))) float f32x16;
typedef __attribute__((ext_vector_type(2))) float f32x2;

#define MFMA(a,b,c) __builtin_amdgcn_mfma_f32_32x32x16_f16((a),(b),(c),0,0,0)

// ---- ws byte offsets ----
#define OB_SLOT      0u          // 200 progress slots (int), 64B stride
#define OB_H0H       16384u      // fp16 [4][32][512] ring (32 KB/slot)
#define OB_H1H       147456u
#define OB_PART      278528u     // f32 [4][64][1024] partial-gate ring (1 MB)
#define OB_STATE_END 1327104u
#define OB_B0        1327104u    // fp32 [2048] combined bias (packed cols)
#define OB_B1        1335296u
#define OB_WF        1343488u    // fp16 [256][512]   Wfc^T
#define OB_W0        1605632u    // fp16 [2048][768]  packed-col-major
#define OB_W1        4751360u    // fp16 [2048][1024]
#define OB_END       8945664u
#define OB_XH        8945664u    // fp16 [32][2048][256]
#define OB_XEND      42500096u

// ---- dynamic LDS ----
#define LS_PT    49152           // W: [0,49152) ; Pt: float[4][32][32]
#define LS_CST   65536           // float[256]
#define LS_TOTAL 66560

__device__ __forceinline__ float sigf(float v) {
    return 1.0f / (1.0f + exp2f(-1.44269504f * v));
}
__device__ __forceinline__ float tanhfast(float v) {
    const float e = exp2f(2.88539008f * v);
    return 1.0f - 2.0f / (e + 1.0f);
}
__device__ __forceinline__ unsigned short h2u(_Float16 h) {
    union { _Float16 h; unsigned short u; } v; v.h = h; return v.u;
}

// uncached (coherence-point) ops; caller drains vmcnt before consuming loads.
__device__ __forceinline__ f16x8 ld128_coh(const unsigned short* p) {
    f16x8 r;
    asm volatile("global_load_dwordx4 %0, %1, off sc0 sc1"
                 : "=v"(r) : "v"(p) : "memory");
    return r;
}
__device__ __forceinline__ f32x2 ld64f_coh(const float* p) {
    f32x2 r;
    asm volatile("global_load_dwordx2 %0, %1, off sc0 sc1"
                 : "=v"(r) : "v"(p) : "memory");
    return r;
}
__device__ __forceinline__ void st64f_coh(float* p, f32x2 v) {
    asm volatile("global_store_dwordx2 %0, %1, off sc0 sc1"
                 :: "v"(p), "v"(v) : "memory");
}
__device__ __forceinline__ int ld_slot(const int* slots, int i) {
    return __hip_atomic_load(&slots[i * 16], __ATOMIC_RELAXED, __HIP_MEMORY_SCOPE_AGENT);
}
__device__ __forceinline__ int packcol(int p) {
    return (((p >> 2) & 3) * H_) + ((p >> 4) << 2) + (p & 3);
}

// ---- repack: W -> packed-col-major fp16 ----
__global__ __launch_bounds__(256) void repack_w(
    const float* __restrict__ s1, const float* __restrict__ s2,
    int k1, int K, int srcld, int dopack, unsigned short* __restrict__ dst)
{
    const int p  = blockIdx.x;
    const int kk = blockIdx.y * 256 + threadIdx.x;
    if (kk >= K) return;
    const int oc = dopack ? packcol(p) : p;
    const float w = (kk < k1) ? s1[(size_t)kk * srcld + oc]
                              : s2[(size_t)(kk - k1) * srcld + oc];
    dst[(size_t)p * K + kk] = h2u((_Float16)w);
}

__global__ __launch_bounds__(256) void repack_bias(
    const float* __restrict__ bx0, const float* __restrict__ bh0,
    const float* __restrict__ bx1, const float* __restrict__ bh1,
    char* __restrict__ wsb)
{
    const int q = blockIdx.x * 256 + threadIdx.x;
    if (q >= 2 * G_) return;
    const int p  = q & (G_ - 1);
    const int oc = packcol(p);
    float* dst = (float*)(wsb + (q < G_ ? OB_B0 : OB_B1));
    dst[p] = (q < G_) ? (bx0[oc] + bh0[oc]) : (bx1[oc] + bh1[oc]);
}

__global__ __launch_bounds__(256) void repack_x(const float* __restrict__ x, char* __restrict__ wsb)
{
    unsigned short* xh = (unsigned short*)(wsb + OB_XH);
    const size_t n = (size_t)B_ * S_ * DIN;
    for (size_t i = (size_t)blockIdx.x * 256 + threadIdx.x; i < n; i += (size_t)gridDim.x * 256)
        xh[i] = h2u((_Float16)x[i]);
}

// ---- L0 matmul body: x (cached) + h0[t-1] (uncached), batch, drain, MFMA ----
__device__ __forceinline__ void phase_mm_l0(
    int k0, int colc, int halfl, int t, int xsplit,
    const float* __restrict__ x, const unsigned short* __restrict__ XH,
    const unsigned short* A1, const unsigned short* Wlds, f32x16& acc)
{
    f16x8 fh[6];
    #pragma unroll
    for (int s = 0; s < 6; ++s) {
        const int kf = k0 + s * 16;
        if (kf < 256) {
            const size_t o = ((size_t)colc * S_ + t) * DIN + kf + halfl * 8;
            if (xsplit) {
                fh[s] = *(const f16x8*)(XH + o);
            } else {
                const float* xp = x + o;
                #pragma unroll
                for (int j = 0; j < 8; ++j) fh[s][j] = (_Float16)xp[j];
            }
        } else {
            fh[s] = ld128_coh(A1 + colc * 512 + (kf - 256) + halfl * 8);
        }
    }
    asm volatile("s_waitcnt vmcnt(0)" ::: "memory");
    __builtin_amdgcn_sched_barrier(0);
    #pragma unroll
    for (int s = 0; s < 6; ++s) {
        const int k8a = ((k0 + s * 16) >> 3) + halfl;
        const f16x8 bw = *(const f16x8*)(Wlds + (k8a * 32 + colc) * 8);
        acc = MFMA(fh[s], bw, acc);
    }
}

// ---- single-source matmul body (L1A: h0[t], L1B: h1[t-1], FC: h1[t]) ----
__device__ __forceinline__ void phase_mm_single(
    int k0, int colc, int halfl,
    const unsigned short* A, const unsigned short* Wlds, f32x16& acc)
{
    f16x8 fh[4];
    #pragma unroll
    for (int s = 0; s < 4; ++s)
        fh[s] = ld128_coh(A + colc * 512 + (k0 + s * 16) + halfl * 8);
    asm volatile("s_waitcnt vmcnt(0)" ::: "memory");
    __builtin_amdgcn_sched_barrier(0);
    #pragma unroll
    for (int s = 0; s < 4; ++s) {
        const int k8a = ((k0 + s * 16) >> 3) + halfl;
        const f16x8 bw = *(const f16x8*)(Wlds + (k8a * 32 + colc) * 8);
        acc = MFMA(fh[s], bw, acc);
    }
}

// ---- persistent dataflow kernel ----
// blocks [0,64): L0 ; [64,128): L1A (h0-half of layer1) ;
//        [128,192): L1B (h1-half + gates) ; [192,200): FC.
// slots[blk] = timesteps completed by block blk (monotone).
// All waits are block-wide, wave-0 polled, register-cached (R12 protocol).
__global__ __launch_bounds__(512, 2) void lstm_persist(
    const float* __restrict__ x, const float* __restrict__ bfc,
    float* __restrict__ out, char* __restrict__ wsb, int xsplit)
{
    extern __shared__ char smem[];
    unsigned short* Wlds = (unsigned short*)smem;
    float* Pt   = (float*)(smem + LS_PT);
    float* cstL = (float*)(smem + LS_CST);
    int* slots  = (int*)(wsb + OB_SLOT);

    const int blk = blockIdx.x, tid = threadIdx.x;
    const int wave = tid >> 6, lane = tid & 63;
    const int colc = lane & 31, halfl = lane >> 5;

    int role, bb;
    if (blk < 64)       { role = 0; bb = blk; }
    else if (blk < 128) { role = 1; bb = blk - 64; }
    else if (blk < 192) { role = 2; bb = blk - 128; }
    else                { role = 3; bb = blk - 192; }

    const int p0 = bb * 32;

    // stage this block's weight K-slice into LDS once: [k8*32 + col][8 fp16]
    {
        const unsigned short* Wg;
        int wstride, rowoff, kcnt;
        if (role == 0)      { Wg = (const unsigned short*)(wsb + OB_W0); wstride = 768;  rowoff = 0;   kcnt = 768; }
        else if (role == 1) { Wg = (const unsigned short*)(wsb + OB_W1); wstride = 1024; rowoff = 0;   kcnt = 512; }
        else if (role == 2) { Wg = (const unsigned short*)(wsb + OB_W1); wstride = 1024; rowoff = 512; kcnt = 512; }
        else                { Wg = (const unsigned short*)(wsb + OB_WF); wstride = 512;  rowoff = 0;   kcnt = 512; }
        for (int idx = tid; idx < (kcnt >> 3) * 32; idx += 512) {
            const int k8 = idx >> 5, cl = idx & 31;
            *(f16x8*)(Wlds + idx * 8) =
                *(const f16x8*)(Wg + ((size_t)(p0 + cl) * wstride + rowoff + k8 * 8));
        }
    }
    for (int i = tid; i < 256; i += 512) cstL[i] = 0.f;
    __syncthreads();

    unsigned short* H0H = (unsigned short*)(wsb + OB_H0H);
    unsigned short* H1H = (unsigned short*)(wsb + OB_H1H);
    float* PART = (float*)(wsb + OB_PART);
    const unsigned short* XH = (const unsigned short*)(wsb + OB_XH);
    const float* Bp = (const float*)(wsb + (role == 2 ? OB_B1 : OB_B0));

    const int kcnt = (role == 0) ? 768 : 512;
    const int k0 = wave * (kcnt >> 3);
    int sA = 0, sB = 0, sC = 0;   // register-cached monotone progress

    for (int t = 0; t < T_; ++t) {
        // ---- block-wide dataflow wait (wave 0 polls; R12 mechanics) ----
        if (tid < 64) {
            if (role == 0) {                 // L0: all L0 >= t ; all L1A >= t-3
                const int tA = t, tB = t - 3;
                for (;;) {
                    bool ok = true;
                    if (sA < tA) sA = ld_slot(slots, lane);          // L0 0..63
                    ok = ok && (sA >= tA);
                    if (sB < tB) sB = ld_slot(slots, 64 + lane);     // L1A 64..127
                    ok = ok && (sB >= tB);
                    if (__all(ok)) break;
                    __builtin_amdgcn_s_sleep(1);
                }
            } else if (role == 1) {          // L1A: all L0 >= t+1 ; pair L1B >= t-3
                const int tA = t + 1, tB = t - 3;
                for (;;) {
                    bool ok = true;
                    if (sA < tA) sA = ld_slot(slots, lane);          // L0 0..63
                    ok = ok && (sA >= tA);
                    if (lane == 0) {
                        if (sB < tB) sB = ld_slot(slots, 128 + bb);  // pair L1B
                        ok = ok && (sB >= tB);
                    }
                    if (__all(ok)) break;
                    __builtin_amdgcn_s_sleep(1);
                }
            } else if (role == 2) {          // L1B: all L1B >= t ; pair L1A >= t+1 ; FC >= t-3
                const int tA = t, tB = t + 1, tC = t - 3;
                for (;;) {
                    bool ok = true;
                    if (sA < tA) sA = ld_slot(slots, 128 + lane);    // L1B 128..191
                    ok = ok && (sA >= tA);
                    if (lane == 0) {
                        if (sB < tB) sB = ld_slot(slots, 64 + bb);   // pair L1A
                        ok = ok && (sB >= tB);
                    }
                    if (lane < 8) {
                        if (sC < tC) sC = ld_slot(slots, 192 + lane);// FC 192..199
                        ok = ok && (sC >= tC);
                    }
                    if (__all(ok)) break;
                    __builtin_amdgcn_s_sleep(1);
                }
            } else {                         // FC: all L1B >= t+1
                const int tA = t + 1;
                for (;;) {
                    if (sA < tA) sA = ld_slot(slots, 128 + lane);
                    if (__all(sA >= tA)) break;
                    __builtin_amdgcn_s_sleep(1);
                }
            }
        }
        __syncthreads();

        const int pw = t & 3, pr = (t + 3) & 3;

        // L1B: pick up the paired L1A partial (uncached, drained in phase_mm)
        f32x2 preg = {0.f, 0.f};
        if (role == 2)
            preg = ld64f_coh(PART + ((size_t)(pw * 64 + bb) << 10) + tid * 2);

        f32x16 acc;
        #pragma unroll
        for (int i = 0; i < 16; ++i) acc[i] = 0.f;

        if (role == 0)
            phase_mm_l0(k0, colc, halfl, t, xsplit, x, XH, H0H + pr * 16384, Wlds, acc);
        else if (role == 1)
            phase_mm_single(k0, colc, halfl, H0H + pw * 16384, Wlds, acc);
        else if (role == 2)
            phase_mm_single(k0, colc, halfl, H1H + pr * 16384, Wlds, acc);
        else
            phase_mm_single(k0, colc, halfl, H1H + pw * 16384, Wlds, acc);

        // cross-wave K-reduce: waves 4-7 store, waves 0-3 accumulate
        if (wave >= 4) {
            #pragma unroll
            for (int rg = 0; rg < 16; ++rg) {
                const int row = (rg & 3) + 8 * (rg >> 2) + 4 * halfl;
                Pt[(wave - 4) * 1024 + row * 32 + colc] = acc[rg];
            }
        }
        __syncthreads();
        if (wave < 4) {
            #pragma unroll
            for (int rg = 0; rg < 16; ++rg) {
                const int row = (rg & 3) + 8 * (rg >> 2) + 4 * halfl;
                Pt[wave * 1024 + row * 32 + colc] += acc[rg];
            }
        }
        __syncthreads();

        if (role == 1) {
            // L1A: write partial gate sums (no bias) to the pair's mailbox
            f32x2 pv;
            #pragma unroll
            for (int ii = 0; ii < 2; ++ii) {
                const int idx = tid * 2 + ii;
                pv[ii] = Pt[idx] + Pt[1024 + idx] + Pt[2048 + idx] + Pt[3072 + idx];
            }
            st64f_coh(PART + ((size_t)(pw * 64 + bb) << 10) + tid * 2, pv);
        } else if (role == 3) {
            #pragma unroll
            for (int ii = 0; ii < 2; ++ii) {
                const int idx = tid * 2 + ii;
                const int r = idx >> 5, c = idx & 31;
                const float v = Pt[idx] + Pt[1024 + idx] + Pt[2048 + idx] + Pt[3072 + idx]
                              + bfc[p0 + c];
                out[((size_t)r * S_ + t) * DOUT + p0 + c] = v;
            }
        } else {
            // L0 / L1B: finish gates
            #pragma unroll
            for (int ii = 0; ii < 2; ++ii) {
                const int idx = tid * 2 + ii;
                float v = Pt[idx] + Pt[1024 + idx] + Pt[2048 + idx] + Pt[3072 + idx]
                        + Bp[p0 + (idx & 31)];
                if (role == 2) v += preg[ii];
                Pt[idx] = v;
            }
            __syncthreads();
            if (tid < 128) {
                const int r = tid >> 2, u2 = (tid & 3) * 2;      // units u2, u2+1
                const int cb = ((u2 >> 2) << 4) + (u2 & 3);
                unsigned short uh[2];
                #pragma unroll
                for (int uu = 0; uu < 2; ++uu) {
                    const float fg = Pt[r * 32 + cb + uu + 0];
                    const float ig = Pt[r * 32 + cb + uu + 4];
                    const float gg = Pt[r * 32 + cb + uu + 8];
                    const float og = Pt[r * 32 + cb + uu + 12];
                    const float cv = cstL[r * 8 + u2 + uu];
                    const float cn = sigf(fg) * cv + sigf(ig) * tanhfast(gg);
                    const float hn = sigf(og) * tanhfast(cn);
                    cstL[r * 8 + u2 + uu] = cn;
                    uh[uu] = h2u((_Float16)hn);
                }
                const unsigned wv = (unsigned)uh[0] | ((unsigned)uh[1] << 16);
                const int off = pw * 16384 + r * 512 + bb * 8 + u2;   // even element
                unsigned short* DH = (role == 0) ? H0H : H1H;
                __hip_atomic_store((unsigned*)(DH + off), wv,
                                   __ATOMIC_RELAXED, __HIP_MEMORY_SCOPE_AGENT);
            }
        }

        // ---- publish (syncthreads drains each wave's stores first) ----
        __syncthreads();
        if (tid == 0)
            __hip_atomic_store(&slots[blk * 16], t + 1,
                               __ATOMIC_RELAXED, __HIP_MEMORY_SCOPE_AGENT);
    }
}

extern "C" void kernel_launch(void* const* d_in, const int* in_sizes, int n_in,
                              void* d_out, int out_size, void* d_ws, size_t ws_size,
                              hipStream_t stream)
{
    const float* x   = (const float*)d_in[0];
    const float* Wx0 = (const float*)d_in[1];
    const float* bx0 = (const float*)d_in[2];
    const float* Wh0 = (const float*)d_in[3];
    const float* bh0 = (const float*)d_in[4];
    const float* Wx1 = (const float*)d_in[5];
    const float* bx1 = (const float*)d_in[6];
    const float* Wh1 = (const float*)d_in[7];
    const float* bh1 = (const float*)d_in[8];
    const float* Wfc = (const float*)d_in[9];
    const float* bfc = (const float*)d_in[10];
    float* out = (float*)d_out;
    char*  wsb = (char*)d_ws;

    const int xsplit = (ws_size >= OB_XEND) ? 1 : 0;

    hipMemsetAsync(d_ws, 0, OB_STATE_END, stream);

    repack_w<<<dim3(G_, 3), 256, 0, stream>>>(Wx0, Wh0, 256, 768, G_, 1,
        (unsigned short*)(wsb + OB_W0));
    repack_w<<<dim3(G_, 4), 256, 0, stream>>>(Wx1, Wh1, 512, 1024, G_, 1,
        (unsigned short*)(wsb + OB_W1));
    repack_w<<<dim3(DOUT, 2), 256, 0, stream>>>(Wfc, Wfc, 512, 512, DOUT, 0,
        (unsigned short*)(wsb + OB_WF));
    repack_bias<<<16, 256, 0, stream>>>(bx0, bh0, bx1, bh1, wsb);
    if (xsplit) repack_x<<<2048, 256, 0, stream>>>(x, wsb);

    hipFuncSetAttribute((const void*)lstm_persist,
                        hipFuncAttributeMaxDynamicSharedMemorySize, LS_TOTAL);
    lstm_persist<<<NBLK, 512, LS_TOTAL, stream>>>(x, bfc, out, wsb, xsplit);
}